// Round 3
// baseline (4471.939 us; speedup 1.0000x reference)
//
#include <hip/hip_runtime.h>
#include <cstdint>
#include <cstddef>
#include <type_traits>
#include <utility>

typedef unsigned short u16;
typedef short short8 __attribute__((ext_vector_type(8)));
typedef __bf16 bf16x8 __attribute__((ext_vector_type(8)));
typedef float float4v __attribute__((ext_vector_type(4)));

// ---------- bf16 <-> f32 ----------
__device__ __forceinline__ float bf2f(u16 u) {
  union { uint32_t i; float f; } v; v.i = ((uint32_t)u) << 16; return v.f;
}
__device__ __forceinline__ u16 f2bf(float f) {
  union { uint32_t i; float f; } v; v.f = f;
  uint32_t u = v.i;
  return (u16)((u + 0x7FFFu + ((u >> 16) & 1u)) >> 16);
}

// ---------- fast transcendentals (saturate cleanly at +-inf) ----------
__device__ __forceinline__ float fsig(float x) {
  float e = __expf(-x);
  return __builtin_amdgcn_rcpf(1.0f + e);
}
__device__ __forceinline__ float ftanh(float x) {
  float e = __expf(2.0f * x);
  return 1.0f - 2.0f * __builtin_amdgcn_rcpf(e + 1.0f);
}

// ---------- cheap workgroup barrier: LDS-only consistency (no vmcnt drain).
__device__ __forceinline__ void bar_lgkm() {
  __builtin_amdgcn_sched_barrier(0);
  asm volatile("s_waitcnt lgkmcnt(0)" ::: "memory");
  __builtin_amdgcn_s_barrier();
  __builtin_amdgcn_sched_barrier(0);
}

// ---------- MFMA wrapper: works whether builtin takes short8 or bf16x8 ----------
template <class V, class = void> struct MfmaTakesShort : std::false_type {};
template <class V>
struct MfmaTakesShort<V, std::void_t<decltype(__builtin_amdgcn_mfma_f32_16x16x32_bf16(
    std::declval<V>(), std::declval<V>(), std::declval<float4v>(), 0, 0, 0))>>
    : std::true_type {};

template <bool UseShort> struct MF {
  template <class V>
  static __device__ __forceinline__ float4v run(V a, V b, float4v c) {
    return __builtin_amdgcn_mfma_f32_16x16x32_bf16(a, b, c, 0, 0, 0);
  }
};
template <> struct MF<false> {
  template <class V>
  static __device__ __forceinline__ float4v run(V a, V b, float4v c) {
    return __builtin_amdgcn_mfma_f32_16x16x32_bf16(
        __builtin_bit_cast(bf16x8, a), __builtin_bit_cast(bf16x8, b), c, 0, 0, 0);
  }
};
__device__ __forceinline__ float4v mfma_bf16(short8 a, short8 b, float4v c) {
  return MF<MfmaTakesShort<short8>::value>::run(a, b, c);
}

// ============================================================================
// Weight conversion: f32 [2048][Kin] -> bf16 [2048][512], zero-padded
// ============================================================================
__global__ void k_cvt_wih(const float* __restrict__ w, u16* __restrict__ o, int Kin) {
  int id = blockIdx.x * 256 + threadIdx.x;   // 2048*512 total
  int n = id >> 9, k = id & 511;
  o[id] = (k < Kin) ? f2bf(w[(long)n * Kin + k]) : (u16)0;
}

// f32 -> bf16 straight convert (w_hh: 2*1024*256 = 524288 elems)
__global__ void k_cvt_whh(const float* __restrict__ w, u16* __restrict__ o) {
  int id = blockIdx.x * 256 + threadIdx.x;
  o[id] = f2bf(w[id]);
}

// ============================================================================
// proj[v][k][nf] = sum_cd emb_char[v][cd] * conv_w[nf][cd][k]   (f32 in, bf16 out)
// ============================================================================
__global__ void k_proj(const float* __restrict__ ec, const float* __restrict__ cw,
                       u16* __restrict__ proj) {
  int v = blockIdx.x, idx = threadIdx.x;
  if (idx >= 300) return;
  int k = idx / 100, nf = idx % 100;
  float s = 0.f;
  for (int cd = 0; cd < 100; cd++)
    s += ec[v * 100 + cd] * cw[(nf * 100 + cd) * 3 + k];
  proj[v * 300 + k * 100 + nf] = f2bf(s);
}

// ============================================================================
// word + pos embedding gather into bf16 x (cols 0..299 word, 400..499 pos,
// 500..511 zero). Char features (300..399) filled by k_charconv.
// ============================================================================
__global__ void k_embed(const int* __restrict__ iw, const int* __restrict__ ip,
                        const float* __restrict__ ew, const float* __restrict__ ep,
                        u16* __restrict__ x) {
  int row = blockIdx.x, j = threadIdx.x;
  u16 v;
  if (j < 300) v = f2bf(ew[(long)iw[row] * 300 + j]);
  else if (j < 400) return;
  else if (j < 500) v = f2bf(ep[ip[row] * 100 + (j - 400)]);
  else v = 0;
  x[row * 512 + j] = v;
}

// ============================================================================
// char conv via proj table in LDS: out[nf] = tanh(b + max_p sum_k proj)
// ============================================================================
__global__ __launch_bounds__(128) void k_charconv(const int* __restrict__ ic,
                                                  const u16* __restrict__ proj,
                                                  const float* __restrict__ cb,
                                                  u16* __restrict__ x) {
  __shared__ u16 pl[30000];
  __shared__ int ids[20];
  int tid = threadIdx.x;
  for (int i = tid; i < 15000; i += 128)
    ((uint32_t*)pl)[i] = ((const uint32_t*)proj)[i];
  float bias = (tid < 100) ? cb[tid] : 0.f;
  for (int r = 0; r < 16; r++) {
    int row = blockIdx.x * 16 + r;
    __syncthreads();  // covers pl load on first iter; protects ids reuse
    if (tid < 20) ids[tid] = ic[row * 20 + tid];
    __syncthreads();
    if (tid < 100) {
      float mx = -1e30f;
      for (int p = 0; p < 22; p++) {
        float s = 0.f;
#pragma unroll
        for (int k = 0; k < 3; k++) {
          int q = p + k - 2;
          if (q >= 0 && q < 20) s += bf2f(pl[ids[q] * 300 + k * 100 + tid]);
        }
        mx = fmaxf(mx, s);
      }
      x[row * 512 + 300 + tid] = f2bf(ftanh(mx + bias));
    }
  }
}

// ============================================================================
// GEMM  C[16384 x 2048] = A[16384 x 512](bf16) @ B[2048 x 512]^T + bias(f32)
// 128x128 tile, BK=64, 4 waves, 16x16x32 MFMA. C fp32 (tier A) or bf16 (tier B).
// ============================================================================
template <bool GXF32>
__global__ __launch_bounds__(256) void k_gemm(const u16* __restrict__ A,
                                              const u16* __restrict__ Bm,
                                              const float* __restrict__ bias,
                                              void* __restrict__ Cv) {
  __shared__ u16 lA[128 * 64];
  __shared__ u16 lB[128 * 64];
  int tid = threadIdx.x;
  int w = tid >> 6, l = tid & 63, q = l >> 4, c16 = l & 15;
  int wm = w >> 1, wn = w & 1;
  int m0 = blockIdx.y * 128, n0 = blockIdx.x * 128;
  float4v acc[4][4];
#pragma unroll
  for (int i = 0; i < 4; i++)
#pragma unroll
    for (int j = 0; j < 4; j++) acc[i][j] = (float4v){0.f, 0.f, 0.f, 0.f};

  for (int kk = 0; kk < 512; kk += 64) {
    __syncthreads();
#pragma unroll
    for (int j = 0; j < 4; j++) {
      int idx = j * 256 + tid;
      int m = idx >> 3, k8 = (idx & 7) * 8;
      *(short8*)(lA + idx * 8) = *(const short8*)(A + (long)(m0 + m) * 512 + kk + k8);
      *(short8*)(lB + idx * 8) = *(const short8*)(Bm + (long)(n0 + m) * 512 + kk + k8);
    }
    __syncthreads();
#pragma unroll
    for (int kt = 0; kt < 2; kt++) {
      short8 af[4], bfv[4];
#pragma unroll
      for (int mt = 0; mt < 4; mt++)
        af[mt] = *(const short8*)(lA + (wm * 64 + mt * 16 + c16) * 64 + kt * 32 + q * 8);
#pragma unroll
      for (int nt = 0; nt < 4; nt++)
        bfv[nt] = *(const short8*)(lB + (wn * 64 + nt * 16 + c16) * 64 + kt * 32 + q * 8);
#pragma unroll
      for (int mt = 0; mt < 4; mt++)
#pragma unroll
        for (int nt = 0; nt < 4; nt++)
          acc[mt][nt] = mfma_bf16(af[mt], bfv[nt], acc[mt][nt]);
    }
  }
#pragma unroll
  for (int mt = 0; mt < 4; mt++)
#pragma unroll
    for (int nt = 0; nt < 4; nt++) {
      int ng = n0 + wn * 64 + nt * 16 + c16;
      float bv = bias[ng];
#pragma unroll
      for (int r = 0; r < 4; r++) {
        long mg = m0 + wm * 64 + mt * 16 + q * 4 + r;
        float val = acc[mt][nt][r] + bv;
        if constexpr (GXF32) ((float*)Cv)[mg * 2048 + ng] = val;
        else ((u16*)Cv)[mg * 2048 + ng] = f2bf(val);
      }
    }
}

// ============================================================================
// LSTM recurrence. 8 blocks = 4 batch-groups x 2 dirs, 512 thr (8 waves).
// Each block owns 16 batch rows end-to-end: zero cross-WG sync.
//
// R2: step is LATENCY-bound at 2 waves/SIMD (static pipe math: MFMA ~614cy,
// VALU ~1100cy per SIMD vs 8290cy measured). Two exposed latencies removed:
//  (1) gx was the MFMA C-operand -> its vmcnt wait sat before the FIRST MFMA
//      with nothing to cover it (~500-900cy, GX=128MB, half L3-absorbed).
//      Now acc starts at 0 and gx is added in the nonlin phase: the loads
//      issued at step top have the whole MFMA phase to land. Same additions,
//      different order (tolerance 1e-3).
//  (2) hls double-buffered: read hls[s&1], write hls[s&1^1], ONE bar_lgkm per
//      step (own lgkmcnt(0) drains both reads+writes before signaling).
//  LDS refit: NREG 46->48, ldsB 18->16 frags (131072 + 16896 = 148KB).
//  Kept from R1: kt-outer a-read reuse, hp-in-registers, deferred stores,
//  imm-offset gx addressing. No inline asm MFMA.
// ============================================================================
template <bool GXF32, bool OUTF32>
__global__ __launch_bounds__(512, 2) void k_recur(const void* __restrict__ gxv,
                                                  const u16* __restrict__ whh,
                                                  const float* __restrict__ mask,
                                                  void* __restrict__ outv) {
  __shared__ u16 ldsB[8 * 16 * 64 * 8];  // 131072 B
  __shared__ u16 hls[2][16 * 264];       // 2 x 8448 B (pad kills b128 bank conflicts)
  constexpr int NREG = 48;
  int tid = threadIdx.x;
  int w = tid >> 6, l = tid & 63, q = l >> 4, c16 = l & 15;
  int bg = blockIdx.x & 3, d = blockIdx.x >> 2;
  int b0 = bg * 16;
  const u16* Wd = whh + d * (1024 * 256);

  for (int i = tid; i < 16 * 264; i += 512) hls[0][i] = 0;
  // hls[1] fully overwritten at s=0 before first read at s=1: no init needed.

  // B fragments: id = f*8 + kt, f = g*2 + hti; coltile nt = g*16 + 2w + hti
  short8 Breg[NREG];
#pragma unroll
  for (int f = 0; f < 8; f++) {
    int nt = (f >> 1) * 16 + 2 * w + (f & 1);
#pragma unroll
    for (int kt = 0; kt < 8; kt++) {
      int id = f * 8 + kt;
      short8 v = *(const short8*)(Wd + (nt * 16 + c16) * 256 + kt * 32 + q * 8);
      if (id < NREG) Breg[id] = v;
      else *(short8*)(ldsB + ((w * 16 + (id - NREG)) * 64 + l) * 8) = v;
    }
  }
  float c_[2][4];
#pragma unroll
  for (int i = 0; i < 2; i++)
#pragma unroll
    for (int r = 0; r < 4; r++) c_[i][r] = 0.f;
  unsigned hprev[4] = {0u, 0u, 0u, 0u};  // packed bf16 of previous hn (this lane's own)
  __syncthreads();

  const float* gxf = (const float*)gxv;
  const u16* gxh = (const u16*)gxv;
  float* outf = (float*)outv;
  u16* outh = (u16*)outv;

  // step-invariant per-lane element offsets (row-major GX), row = b0+q*4+r
  int rb[4];
#pragma unroll
  for (int r = 0; r < 4; r++)
    rb[r] = (b0 + q * 4 + r) * 524288 + 2 * w * 16 + c16;
  const float* mrow = mask + (b0 + q * 4) * 256;

#pragma unroll 1
  for (int s = 0; s < 256; s++) {
    int t = d ? (255 - s) : s;
    const u16* hrd = hls[s & 1];
    u16* hwr = hls[(s & 1) ^ 1];

    // -------- issue gx + mask loads; consumed only AFTER the MFMA phase ----
    float m4[4];
#pragma unroll
    for (int r = 0; r < 4; r++) m4[r] = mrow[r * 256 + t];

    float gxr[8][4];  // gx values, f = g*2 + hti
    if constexpr (GXF32) {
      const float* gxs = gxf + (size_t)t * 2048 + d * 1024;
#pragma unroll
      for (int r = 0; r < 4; r++) {
        const float* p = gxs + rb[r];
#pragma unroll
        for (int f = 0; f < 8; f++)
          gxr[f][r] = p[(f >> 1) * 256 + (f & 1) * 16];  // imm offset
      }
    } else {
      const u16* gxs = gxh + (size_t)t * 2048 + d * 1024;
#pragma unroll
      for (int r = 0; r < 4; r++) {
        const u16* p = gxs + rb[r];
#pragma unroll
        for (int f = 0; f < 8; f++)
          gxr[f][r] = bf2f(p[(f >> 1) * 256 + (f & 1) * 16]);
      }
    }
    __builtin_amdgcn_sched_barrier(0);  // pin load issue above the MFMA body

    // gates = h @ w_hh^T (acc from 0); kt-outer so each a-frag read once
    float4v acc[8];
#pragma unroll
    for (int f = 0; f < 8; f++) acc[f] = (float4v){0.f, 0.f, 0.f, 0.f};
#pragma unroll
    for (int kt = 0; kt < 8; kt++) {
      short8 a = *(const short8*)(hrd + c16 * 264 + kt * 32 + q * 8);
#pragma unroll
      for (int f = 0; f < 8; f++) {
        int id = f * 8 + kt;
        short8 bb = (id < NREG)
                        ? Breg[id]
                        : *(const short8*)(ldsB + ((w * 16 + (id - NREG)) * 64 + l) * 8);
        acc[f] = mfma_bf16(a, bb, acc[f]);
      }
    }

    // nonlinearity; gate = acc + gxr (gx latency hidden under MFMA phase);
    // hp extracted from hprev (bf16-exact, same value hls held)
    unsigned hnew[4];
    float hf[8];  // f32 hn held for deferred store (DCE'd when !OUTF32)
#pragma unroll
    for (int hti = 0; hti < 2; hti++) {
      unsigned p0 = 0u, p1 = 0u;
#pragma unroll
      for (int r = 0; r < 4; r++) {
        float mt = m4[r];
        float iv = fsig(acc[0 + hti][r] + gxr[0 + hti][r]);   // f = g*2+hti
        float fv = fsig(acc[2 + hti][r] + gxr[2 + hti][r]);
        float gv = ftanh(acc[4 + hti][r] + gxr[4 + hti][r]);
        float ov = fsig(acc[6 + hti][r] + gxr[6 + hti][r]);
        unsigned hpw = hprev[hti * 2 + (r >> 1)];
        union { uint32_t i; float f; } hu;
        hu.i = (r & 1) ? (hpw & 0xFFFF0000u) : (hpw << 16);
        float hpo = hu.f;
        float cn = fv * c_[hti][r] + iv * gv;
        float hn = ov * ftanh(cn);
        hn = mt * hn + (1.f - mt) * hpo;
        cn = mt * cn + (1.f - mt) * c_[hti][r];
        c_[hti][r] = cn;
        hf[hti * 4 + r] = hn;
        unsigned hb = (unsigned)f2bf(hn) << ((r & 1) * 16);
        if (r < 2) p0 |= hb; else p1 |= hb;
      }
      hnew[hti * 2 + 0] = p0;
      hnew[hti * 2 + 1] = p1;
    }

    // write hn into the OTHER hls buffer (read next step) — no conflict with
    // this step's reads, so a single barrier suffices.
#pragma unroll
    for (int hti = 0; hti < 2; hti++)
#pragma unroll
      for (int r = 0; r < 4; r++) {
        u16 hb = (u16)(hnew[hti * 2 + (r >> 1)] >> ((r & 1) * 16));
        hwr[(q * 4 + r) * 264 + (2 * w + hti) * 16 + c16] = hb;
      }
    bar_lgkm();  // own reads (a-frags) + writes drained, then workgroup sync

    // deferred output stores: overlap the NEXT step's load/MFMA phase
#pragma unroll
    for (int r = 0; r < 4; r++) {
      long base = ((long)((b0 + q * 4 + r) * 256 + t)) * 512 + d * 256 + 2 * w * 16 + c16;
      if constexpr (OUTF32) {
        outf[base] = hf[r];            // hti = 0
        outf[base + 16] = hf[4 + r];   // hti = 1
      } else {
        outh[base] = (u16)(hnew[(r >> 1)] >> ((r & 1) * 16));
        outh[base + 16] = (u16)(hnew[2 + (r >> 1)] >> ((r & 1) * 16));
      }
    }
#pragma unroll
    for (int i = 0; i < 4; i++) hprev[i] = hnew[i];
  }
}

// ============================================================================
extern "C" void kernel_launch(void* const* d_in, const int* in_sizes, int n_in,
                              void* d_out, int out_size, void* d_ws, size_t ws_size,
                              hipStream_t stream) {
  const int* iw = (const int*)d_in[0];
  const int* ic = (const int*)d_in[1];
  const int* ip = (const int*)d_in[2];
  const float* mask = (const float*)d_in[3];
  const float* ew = (const float*)d_in[4];
  const float* ec = (const float*)d_in[5];
  const float* ep = (const float*)d_in[6];
  const float* cw = (const float*)d_in[7];
  const float* cb = (const float*)d_in[8];
  const float* wih[3] = {(const float*)d_in[9], (const float*)d_in[12], (const float*)d_in[15]};
  const float* whh[3] = {(const float*)d_in[10], (const float*)d_in[13], (const float*)d_in[16]};
  const float* bs[3] = {(const float*)d_in[11], (const float*)d_in[14], (const float*)d_in[17]};

  char* ws = (char*)d_ws;
  size_t szX0 = (size_t)16384 * 512 * 2;
  size_t szGXf = (size_t)16384 * 2048 * 4;
  size_t szWIH = (size_t)2048 * 512 * 2;
  size_t szWHH = (size_t)2 * 1024 * 256 * 2;
  size_t szPROJ = 60032;
  bool f32gx = ws_size >= szX0 + szGXf + szWIH + szWHH + szPROJ;

  size_t off = 0;
  u16* X0 = (u16*)(ws + off); off += szX0;
  void* GX = (void*)(ws + off); off += f32gx ? szGXf : (szGXf / 2);
  u16* WIHB = (u16*)(ws + off); off += szWIH;
  u16* WHHB = (u16*)(ws + off); off += szWHH;
  u16* PROJ = (u16*)(ws + off);
  u16* X1 = (u16*)d_out;  // bf16 staging in d_out; dead before final f32 write

  hipLaunchKernelGGL(k_proj, dim3(100), dim3(320), 0, stream, ec, cw, PROJ);
  hipLaunchKernelGGL(k_embed, dim3(16384), dim3(512), 0, stream, iw, ip, ew, ep, X0);
  hipLaunchKernelGGL(k_charconv, dim3(1024), dim3(128), 0, stream, ic, PROJ, cb, X0);

  const u16* Xin[3] = {X0, X1, X0};
  void* Xout[3] = {(void*)X1, (void*)X0, d_out};
  int Kin[3] = {500, 512, 512};

  for (int lyr = 0; lyr < 3; lyr++) {
    hipLaunchKernelGGL(k_cvt_wih, dim3(4096), dim3(256), 0, stream, wih[lyr], WIHB, Kin[lyr]);
    hipLaunchKernelGGL(k_cvt_whh, dim3(2048), dim3(256), 0, stream, whh[lyr], WHHB);
    if (f32gx) {
      hipLaunchKernelGGL((k_gemm<true>), dim3(16, 128), dim3(256), 0, stream,
                         Xin[lyr], WIHB, bs[lyr], GX);
      if (lyr < 2)
        hipLaunchKernelGGL((k_recur<true, false>), dim3(8), dim3(512), 0, stream,
                           GX, WHHB, mask, Xout[lyr]);
      else
        hipLaunchKernelGGL((k_recur<true, true>), dim3(8), dim3(512), 0, stream,
                           GX, WHHB, mask, Xout[lyr]);
    } else {
      hipLaunchKernelGGL((k_gemm<false>), dim3(16, 128), dim3(256), 0, stream,
                         Xin[lyr], WIHB, bs[lyr], GX);
      if (lyr < 2)
        hipLaunchKernelGGL((k_recur<false, false>), dim3(8), dim3(512), 0, stream,
                           GX, WHHB, mask, Xout[lyr]);
      else
        hipLaunchKernelGGL((k_recur<false, true>), dim3(8), dim3(512), 0, stream,
                           GX, WHHB, mask, Xout[lyr]);
    }
  }
}

// Round 4
// 2869.579 us; speedup vs baseline: 1.5584x; 1.5584x over previous
//
#include <hip/hip_runtime.h>
#include <cstdint>
#include <cstddef>
#include <type_traits>
#include <utility>

typedef unsigned short u16;
typedef short short8 __attribute__((ext_vector_type(8)));
typedef __bf16 bf16x8 __attribute__((ext_vector_type(8)));
typedef float float4v __attribute__((ext_vector_type(4)));

// ---------- bf16 <-> f32 ----------
__device__ __forceinline__ float bf2f(u16 u) {
  union { uint32_t i; float f; } v; v.i = ((uint32_t)u) << 16; return v.f;
}
__device__ __forceinline__ u16 f2bf(float f) {
  union { uint32_t i; float f; } v; v.f = f;
  uint32_t u = v.i;
  return (u16)((u + 0x7FFFu + ((u >> 16) & 1u)) >> 16);
}

// ---------- fast transcendentals (saturate cleanly at +-inf) ----------
__device__ __forceinline__ float fsig(float x) {
  float e = __expf(-x);
  return __builtin_amdgcn_rcpf(1.0f + e);
}
__device__ __forceinline__ float ftanh(float x) {
  float e = __expf(2.0f * x);
  return 1.0f - 2.0f * __builtin_amdgcn_rcpf(e + 1.0f);
}

// ---------- cheap workgroup barrier: LDS-only consistency (no vmcnt drain).
__device__ __forceinline__ void bar_lgkm() {
  __builtin_amdgcn_sched_barrier(0);
  asm volatile("s_waitcnt lgkmcnt(0)" ::: "memory");
  __builtin_amdgcn_s_barrier();
  __builtin_amdgcn_sched_barrier(0);
}

// ---------- MFMA wrapper: works whether builtin takes short8 or bf16x8 ----------
template <class V, class = void> struct MfmaTakesShort : std::false_type {};
template <class V>
struct MfmaTakesShort<V, std::void_t<decltype(__builtin_amdgcn_mfma_f32_16x16x32_bf16(
    std::declval<V>(), std::declval<V>(), std::declval<float4v>(), 0, 0, 0))>>
    : std::true_type {};

template <bool UseShort> struct MF {
  template <class V>
  static __device__ __forceinline__ float4v run(V a, V b, float4v c) {
    return __builtin_amdgcn_mfma_f32_16x16x32_bf16(a, b, c, 0, 0, 0);
  }
};
template <> struct MF<false> {
  template <class V>
  static __device__ __forceinline__ float4v run(V a, V b, float4v c) {
    return __builtin_amdgcn_mfma_f32_16x16x32_bf16(
        __builtin_bit_cast(bf16x8, a), __builtin_bit_cast(bf16x8, b), c, 0, 0, 0);
  }
};
__device__ __forceinline__ float4v mfma_bf16(short8 a, short8 b, float4v c) {
  return MF<MfmaTakesShort<short8>::value>::run(a, b, c);
}

// ============================================================================
// Weight conversion: f32 [2048][Kin] -> bf16 [2048][512], zero-padded
// ============================================================================
__global__ void k_cvt_wih(const float* __restrict__ w, u16* __restrict__ o, int Kin) {
  int id = blockIdx.x * 256 + threadIdx.x;   // 2048*512 total
  int n = id >> 9, k = id & 511;
  o[id] = (k < Kin) ? f2bf(w[(long)n * Kin + k]) : (u16)0;
}

// f32 -> bf16 straight convert (w_hh: 2*1024*256 = 524288 elems)
__global__ void k_cvt_whh(const float* __restrict__ w, u16* __restrict__ o) {
  int id = blockIdx.x * 256 + threadIdx.x;
  o[id] = f2bf(w[id]);
}

// ============================================================================
// proj[v][k][nf] = sum_cd emb_char[v][cd] * conv_w[nf][cd][k]   (f32 in, bf16 out)
// ============================================================================
__global__ void k_proj(const float* __restrict__ ec, const float* __restrict__ cw,
                       u16* __restrict__ proj) {
  int v = blockIdx.x, idx = threadIdx.x;
  if (idx >= 300) return;
  int k = idx / 100, nf = idx % 100;
  float s = 0.f;
  for (int cd = 0; cd < 100; cd++)
    s += ec[v * 100 + cd] * cw[(nf * 100 + cd) * 3 + k];
  proj[v * 300 + k * 100 + nf] = f2bf(s);
}

// ============================================================================
// word + pos embedding gather into bf16 x (cols 0..299 word, 400..499 pos,
// 500..511 zero). Char features (300..399) filled by k_charconv.
// ============================================================================
__global__ void k_embed(const int* __restrict__ iw, const int* __restrict__ ip,
                        const float* __restrict__ ew, const float* __restrict__ ep,
                        u16* __restrict__ x) {
  int row = blockIdx.x, j = threadIdx.x;
  u16 v;
  if (j < 300) v = f2bf(ew[(long)iw[row] * 300 + j]);
  else if (j < 400) return;
  else if (j < 500) v = f2bf(ep[ip[row] * 100 + (j - 400)]);
  else v = 0;
  x[row * 512 + j] = v;
}

// ============================================================================
// char conv via proj table in LDS: out[nf] = tanh(b + max_p sum_k proj)
// ============================================================================
__global__ __launch_bounds__(128) void k_charconv(const int* __restrict__ ic,
                                                  const u16* __restrict__ proj,
                                                  const float* __restrict__ cb,
                                                  u16* __restrict__ x) {
  __shared__ u16 pl[30000];
  __shared__ int ids[20];
  int tid = threadIdx.x;
  for (int i = tid; i < 15000; i += 128)
    ((uint32_t*)pl)[i] = ((const uint32_t*)proj)[i];
  float bias = (tid < 100) ? cb[tid] : 0.f;
  for (int r = 0; r < 16; r++) {
    int row = blockIdx.x * 16 + r;
    __syncthreads();  // covers pl load on first iter; protects ids reuse
    if (tid < 20) ids[tid] = ic[row * 20 + tid];
    __syncthreads();
    if (tid < 100) {
      float mx = -1e30f;
      for (int p = 0; p < 22; p++) {
        float s = 0.f;
#pragma unroll
        for (int k = 0; k < 3; k++) {
          int q = p + k - 2;
          if (q >= 0 && q < 20) s += bf2f(pl[ids[q] * 300 + k * 100 + tid]);
        }
        mx = fmaxf(mx, s);
      }
      x[row * 512 + 300 + tid] = f2bf(ftanh(mx + bias));
    }
  }
}

// ============================================================================
// GEMM  C[16384 x 2048] = A[16384 x 512](bf16) @ B[2048 x 512]^T + bias(f32)
// 128x128 tile, BK=64, 4 waves, 16x16x32 MFMA. C fp32 (tier A) or bf16 (tier B).
// ============================================================================
template <bool GXF32>
__global__ __launch_bounds__(256) void k_gemm(const u16* __restrict__ A,
                                              const u16* __restrict__ Bm,
                                              const float* __restrict__ bias,
                                              void* __restrict__ Cv) {
  __shared__ u16 lA[128 * 64];
  __shared__ u16 lB[128 * 64];
  int tid = threadIdx.x;
  int w = tid >> 6, l = tid & 63, q = l >> 4, c16 = l & 15;
  int wm = w >> 1, wn = w & 1;
  int m0 = blockIdx.y * 128, n0 = blockIdx.x * 128;
  float4v acc[4][4];
#pragma unroll
  for (int i = 0; i < 4; i++)
#pragma unroll
    for (int j = 0; j < 4; j++) acc[i][j] = (float4v){0.f, 0.f, 0.f, 0.f};

  for (int kk = 0; kk < 512; kk += 64) {
    __syncthreads();
#pragma unroll
    for (int j = 0; j < 4; j++) {
      int idx = j * 256 + tid;
      int m = idx >> 3, k8 = (idx & 7) * 8;
      *(short8*)(lA + idx * 8) = *(const short8*)(A + (long)(m0 + m) * 512 + kk + k8);
      *(short8*)(lB + idx * 8) = *(const short8*)(Bm + (long)(n0 + m) * 512 + kk + k8);
    }
    __syncthreads();
#pragma unroll
    for (int kt = 0; kt < 2; kt++) {
      short8 af[4], bfv[4];
#pragma unroll
      for (int mt = 0; mt < 4; mt++)
        af[mt] = *(const short8*)(lA + (wm * 64 + mt * 16 + c16) * 64 + kt * 32 + q * 8);
#pragma unroll
      for (int nt = 0; nt < 4; nt++)
        bfv[nt] = *(const short8*)(lB + (wn * 64 + nt * 16 + c16) * 64 + kt * 32 + q * 8);
#pragma unroll
      for (int mt = 0; mt < 4; mt++)
#pragma unroll
        for (int nt = 0; nt < 4; nt++)
          acc[mt][nt] = mfma_bf16(af[mt], bfv[nt], acc[mt][nt]);
    }
  }
#pragma unroll
  for (int mt = 0; mt < 4; mt++)
#pragma unroll
    for (int nt = 0; nt < 4; nt++) {
      int ng = n0 + wn * 64 + nt * 16 + c16;
      float bv = bias[ng];
#pragma unroll
      for (int r = 0; r < 4; r++) {
        long mg = m0 + wm * 64 + mt * 16 + q * 4 + r;
        float val = acc[mt][nt][r] + bv;
        if constexpr (GXF32) ((float*)Cv)[mg * 2048 + ng] = val;
        else ((u16*)Cv)[mg * 2048 + ng] = f2bf(val);
      }
    }
}

// ============================================================================
// LSTM recurrence, COLUMN-SPLIT: 16 blocks = 8 pairs (4 bg x 2 dir) x 2 halves.
// Why: w_hh residency (512KB/dir) fills a CU's entire 2048-VGPR file, capping
// occupancy at 2 waves/SIMD with VALU ~3300cy + MFMA ~2000cy per SIMD per step
// (R0-R2 evidence: all intra-CU scheduling fixes were flat; R2's +40 regs
// spilled and cost 1.5x). Splitting the 256 h-columns across 2 CUs halves
// Breg (32 frags = 128 VGPR), MFMA (32/wave), nonlin (4 h/lane) and gx
// (16 loads/lane) per CU.
//
// Per-step h-exchange between pair halves:
//  - write own h-half (col-major u64: 4 rows x 1 col) to hx slot via
//    agent-scope atomic stores; slots double-buffered by step parity.
//  - __syncthreads (drains vmcnt) -> tid0 sets flags[s] (release-agent),
//    polls partner's flags[s] (acquire-agent, iteration-capped so a sync bug
//    fails absmax instead of hanging) -> __syncthreads -> all threads ingest
//    partner 8B (relaxed-agent, bypasses L1) -> ds_write -> bar_lgkm.
//  - Safety: partner reuses slot par at s+2 only after it consumed my
//    flags(s+1), which I set only after my ingest of slot s completed.
//  - flags are fresh per step and memset before each dispatch (replay-safe).
//  - block mapping pair=blk&7, half=blk>>3 puts both halves of a pair on the
//    SAME XCD under round-robin dispatch -> exchange via shared L2.
// gx consumed as MFMA C-operand (R1 semantics; R2's split-add spilled).
// ============================================================================
template <bool GXF32, bool OUTF32>
__global__ __launch_bounds__(512, 2) void k_recur(
    const void* __restrict__ gxv, const u16* __restrict__ whh,
    const float* __restrict__ mask, void* __restrict__ outv,
    unsigned long long* __restrict__ hx, unsigned* __restrict__ flags) {
  __shared__ u16 hls[2][16 * 264];  // 2 x 8448 B (pad kills b128 bank conflicts)
  int tid = threadIdx.x;
  int w = tid >> 6, l = tid & 63, q = l >> 4, c16 = l & 15;
  int blk = blockIdx.x;
  int pair = blk & 7, half = blk >> 3;   // pair-mates land on same XCD
  int bg = pair >> 1, d = pair & 1;
  int b0 = bg * 16;
  int ht = half * 8 + w;                 // global h-coltile 0..15
  const u16* Wd = whh + d * (1024 * 256);

  for (int i = tid; i < 2 * 16 * 264; i += 512) ((u16*)hls)[i] = 0;

  // B fragments: 4 gate-tiles (g=0..3), gate-coltile gt = g*16 + ht.
  // 32 frags = 128 VGPRs, all resident (no LDS spill needed).
  short8 Breg[32];
#pragma unroll
  for (int g = 0; g < 4; g++)
#pragma unroll
    for (int kt = 0; kt < 8; kt++)
      Breg[g * 8 + kt] =
          *(const short8*)(Wd + ((g * 16 + ht) * 16 + c16) * 256 + kt * 32 + q * 8);

  float c_[4] = {0.f, 0.f, 0.f, 0.f};
  unsigned hprev[2] = {0u, 0u};  // packed bf16 of this lane's previous hn (4 rows)
  __syncthreads();

  const float* gxf = (const float*)gxv;
  const u16* gxh = (const u16*)gxv;
  float* outf = (float*)outv;
  u16* outh = (u16*)outv;

  // step-invariant per-lane element offsets (row-major GX), row = b0+q*4+r
  int rb[4];
#pragma unroll
  for (int r = 0; r < 4; r++)
    rb[r] = (b0 + q * 4 + r) * 524288 + d * 1024 + ht * 16 + c16;
  const float* mrow = mask + (b0 + q * 4) * 256;

#pragma unroll 1
  for (int s = 0; s < 256; s++) {
    int t = d ? (255 - s) : s;
    const u16* hrd = hls[s & 1];
    u16* hwr = hls[(s & 1) ^ 1];
    int par = (s & 1) ^ 1;

    float m4[4];
#pragma unroll
    for (int r = 0; r < 4; r++) m4[r] = mrow[r * 256 + t];

    // acc init = gx (MFMA C operand); gate col = g*256 + ht*16 + c16 (+d*1024)
    float4v acc[4];
    if constexpr (GXF32) {
      const float* gxs = gxf + (size_t)t * 2048;
#pragma unroll
      for (int r = 0; r < 4; r++) {
        const float* p = gxs + rb[r];
#pragma unroll
        for (int g = 0; g < 4; g++) acc[g][r] = p[g * 256];  // imm offset
      }
    } else {
      const u16* gxs = gxh + (size_t)t * 2048;
#pragma unroll
      for (int r = 0; r < 4; r++) {
        const u16* p = gxs + rb[r];
#pragma unroll
        for (int g = 0; g < 4; g++) acc[g][r] = bf2f(p[g * 256]);
      }
    }
    __builtin_amdgcn_sched_barrier(0);  // pin load issue above the MFMA body

    // gates += h @ w_hh^T ; full 256-dim K (needs full h from both halves)
#pragma unroll
    for (int kt = 0; kt < 8; kt++) {
      short8 a = *(const short8*)(hrd + c16 * 264 + kt * 32 + q * 8);
#pragma unroll
      for (int g = 0; g < 4; g++)
        acc[g] = mfma_bf16(a, Breg[g * 8 + kt], acc[g]);
    }

    // nonlinearity: 4 h-values/lane (rows q*4+r, h-col ht*16+c16)
    unsigned p0 = 0u, p1 = 0u;
    float hfv[4];
#pragma unroll
    for (int r = 0; r < 4; r++) {
      float mt = m4[r];
      float iv = fsig(acc[0][r]);
      float fv = fsig(acc[1][r]);
      float gv = ftanh(acc[2][r]);
      float ov = fsig(acc[3][r]);
      unsigned hpw = hprev[r >> 1];
      union { uint32_t i; float f; } hu;
      hu.i = (r & 1) ? (hpw & 0xFFFF0000u) : (hpw << 16);
      float hpo = hu.f;
      float cn = fv * c_[r] + iv * gv;
      float hn = ov * ftanh(cn);
      hn = mt * hn + (1.f - mt) * hpo;
      cn = mt * cn + (1.f - mt) * c_[r];
      c_[r] = cn;
      hfv[r] = hn;
      unsigned hb = (unsigned)f2bf(hn) << ((r & 1) * 16);
      if (r < 2) p0 |= hb; else p1 |= hb;
    }

    // local h -> hls[par] (own 128 cols)
#pragma unroll
    for (int r = 0; r < 4; r++) {
      u16 hb = (u16)(((r < 2) ? p0 : p1) >> ((r & 1) * 16));
      hwr[(q * 4 + r) * 264 + ht * 16 + c16] = hb;
    }
    // own h-half -> hx slot (col-major: u64 = 4 rows of one col), agent scope
    {
      size_t hxi = (size_t)((pair * 2 + par) * 2 + half) * 512 + (w * 16 + c16) * 4 + q;
      unsigned long long hv = ((unsigned long long)p1 << 32) | (unsigned long long)p0;
      __hip_atomic_store(&hx[hxi], hv, __ATOMIC_RELAXED, __HIP_MEMORY_SCOPE_AGENT);
    }
    // output stores
#pragma unroll
    for (int r = 0; r < 4; r++) {
      long oidx = ((long)((b0 + q * 4 + r) * 256 + t)) * 512 + d * 256 + ht * 16 + c16;
      if constexpr (OUTF32) outf[oidx] = hfv[r];
      else outh[oidx] = (u16)(((r < 2) ? p0 : p1) >> ((r & 1) * 16));
    }

    __syncthreads();  // drains vmcnt(0): hx stores complete at agent scope
    if (tid == 0) {
      __hip_atomic_store(&flags[s * 16 + pair * 2 + half], 1u,
                         __ATOMIC_RELEASE, __HIP_MEMORY_SCOPE_AGENT);
      unsigned cnt = 0;
      while (__hip_atomic_load(&flags[s * 16 + pair * 2 + (half ^ 1)],
                               __ATOMIC_ACQUIRE, __HIP_MEMORY_SCOPE_AGENT) == 0u) {
        if (++cnt > 4000000u) break;  // fail visibly (absmax) instead of hang
        __builtin_amdgcn_s_sleep(1);
      }
    }
    __syncthreads();

    // ingest partner half: thread tid -> u64 (col pc, rows qq*4+0..3)
    {
      size_t pxi = (size_t)((pair * 2 + par) * 2 + (half ^ 1)) * 512 + tid;
      unsigned long long pv =
          __hip_atomic_load(&hx[pxi], __ATOMIC_RELAXED, __HIP_MEMORY_SCOPE_AGENT);
      int pc = tid >> 2, qq = tid & 3;
      int gcol = (half ^ 1) * 128 + pc;
#pragma unroll
      for (int r = 0; r < 4; r++)
        hwr[(qq * 4 + r) * 264 + gcol] = (u16)(pv >> (r * 16));
    }
    bar_lgkm();  // partner ds_writes visible before next step's reads

    hprev[0] = p0; hprev[1] = p1;
  }
}

// ============================================================================
extern "C" void kernel_launch(void* const* d_in, const int* in_sizes, int n_in,
                              void* d_out, int out_size, void* d_ws, size_t ws_size,
                              hipStream_t stream) {
  const int* iw = (const int*)d_in[0];
  const int* ic = (const int*)d_in[1];
  const int* ip = (const int*)d_in[2];
  const float* mask = (const float*)d_in[3];
  const float* ew = (const float*)d_in[4];
  const float* ec = (const float*)d_in[5];
  const float* ep = (const float*)d_in[6];
  const float* cw = (const float*)d_in[7];
  const float* cb = (const float*)d_in[8];
  const float* wih[3] = {(const float*)d_in[9], (const float*)d_in[12], (const float*)d_in[15]};
  const float* whh[3] = {(const float*)d_in[10], (const float*)d_in[13], (const float*)d_in[16]};
  const float* bs[3] = {(const float*)d_in[11], (const float*)d_in[14], (const float*)d_in[17]};

  char* ws = (char*)d_ws;
  size_t szX0 = (size_t)16384 * 512 * 2;
  size_t szGXf = (size_t)16384 * 2048 * 4;
  size_t szWIH = (size_t)2048 * 512 * 2;
  size_t szWHH = (size_t)2 * 1024 * 256 * 2;
  size_t szPROJ = 60032;
  size_t szHX = (size_t)8 * 2 * 2 * 4096;   // pairs x parity x half x 4KB = 128KB
  size_t szFLG = (size_t)256 * 16 * 4;      // per-step fresh flags, 16KB
  bool f32gx = ws_size >= szX0 + szGXf + szWIH + szWHH + szPROJ + szHX + szFLG;

  size_t off = 0;
  u16* X0 = (u16*)(ws + off); off += szX0;
  void* GX = (void*)(ws + off); off += f32gx ? szGXf : (szGXf / 2);
  u16* WIHB = (u16*)(ws + off); off += szWIH;
  u16* WHHB = (u16*)(ws + off); off += szWHH;
  u16* PROJ = (u16*)(ws + off); off += szPROJ;
  unsigned long long* HX = (unsigned long long*)(ws + off); off += szHX;
  unsigned* FLG = (unsigned*)(ws + off);
  u16* X1 = (u16*)d_out;  // bf16 staging in d_out; dead before final f32 write

  hipLaunchKernelGGL(k_proj, dim3(100), dim3(320), 0, stream, ec, cw, PROJ);
  hipLaunchKernelGGL(k_embed, dim3(16384), dim3(512), 0, stream, iw, ip, ew, ep, X0);
  hipLaunchKernelGGL(k_charconv, dim3(1024), dim3(128), 0, stream, ic, PROJ, cb, X0);

  const u16* Xin[3] = {X0, X1, X0};
  void* Xout[3] = {(void*)X1, (void*)X0, d_out};
  int Kin[3] = {500, 512, 512};

  for (int lyr = 0; lyr < 3; lyr++) {
    hipLaunchKernelGGL(k_cvt_wih, dim3(4096), dim3(256), 0, stream, wih[lyr], WIHB, Kin[lyr]);
    hipLaunchKernelGGL(k_cvt_whh, dim3(2048), dim3(256), 0, stream, whh[lyr], WHHB);
    hipMemsetAsync(FLG, 0, szFLG, stream);  // fresh flags per dispatch (replay-safe)
    if (f32gx) {
      hipLaunchKernelGGL((k_gemm<true>), dim3(16, 128), dim3(256), 0, stream,
                         Xin[lyr], WIHB, bs[lyr], GX);
      if (lyr < 2)
        hipLaunchKernelGGL((k_recur<true, false>), dim3(16), dim3(512), 0, stream,
                           GX, WHHB, mask, Xout[lyr], HX, FLG);
      else
        hipLaunchKernelGGL((k_recur<true, true>), dim3(16), dim3(512), 0, stream,
                           GX, WHHB, mask, Xout[lyr], HX, FLG);
    } else {
      hipLaunchKernelGGL((k_gemm<false>), dim3(16, 128), dim3(256), 0, stream,
                         Xin[lyr], WIHB, bs[lyr], GX);
      if (lyr < 2)
        hipLaunchKernelGGL((k_recur<false, false>), dim3(16), dim3(512), 0, stream,
                           GX, WHHB, mask, Xout[lyr], HX, FLG);
      else
        hipLaunchKernelGGL((k_recur<false, true>), dim3(16), dim3(512), 0, stream,
                           GX, WHHB, mask, Xout[lyr], HX, FLG);
    }
  }
}